// Round 3
// baseline (379.200 us; speedup 1.0000x reference)
//
#include <hip/hip_runtime.h>

typedef _Float16 half_t;
typedef _Float16 half8 __attribute__((ext_vector_type(8)));
typedef float f32x4 __attribute__((ext_vector_type(4)));

#define D_EMBED   1024
#define D_CROSS   768
#define N_HEADS   8
#define D_HEAD    128
#define BATCH     8
#define SEQ_Q     4096
#define SEQ_KV    77
#define M_Q       (BATCH*SEQ_Q)     /* 32768 */
#define ROWS_KV   (BATCH*SEQ_KV)    /* 616   */
#define ROWS_KV_PAD 640

// ---------------- workspace layout (bytes) ----------------
#define WS_Q     ((size_t)0)                                  // q (swizzled fp16), attn-out in place
#define WS_WQT   (WS_Q    + (size_t)M_Q*D_EMBED*2)            // Wq^T fp16 [1024][1024] swizzled
#define WS_WOT   (WS_WQT  + (size_t)D_EMBED*D_EMBED*2)        // Wo^T fp16 [1024][1024] swizzled
#define WS_WKVT  (WS_WOT  + (size_t)D_EMBED*D_EMBED*2)        // [Wk;Wv]^T fp16 [2048][768] plain
#define WS_YH    (WS_WKVT + (size_t)2*D_EMBED*D_CROSS*2)      // y fp16 padded [640][768]
#define WS_KV    (WS_YH   + (size_t)ROWS_KV_PAD*D_CROSS*2)    // kv fp16 [640][2048] plain
#define WS_BKV   (WS_KV   + (size_t)ROWS_KV_PAD*2*D_EMBED*2)  // bias concat fp32 [2048]

__device__ __forceinline__ void gload_lds16(const void* g, void* lds) {
  __builtin_amdgcn_global_load_lds(
      (const __attribute__((address_space(1))) unsigned int*)g,
      (__attribute__((address_space(3))) unsigned int*)lds, 16, 0, 0);
}
__device__ __forceinline__ void BAR() {
  __builtin_amdgcn_s_barrier();
  __builtin_amdgcn_sched_barrier(0);
}

// ---------------- prep kernels ----------------
// dst[n][k] = (half) src[k][n]; SWZ: XOR byte bits[5:4] with (n>>1)&3 (LDS-read swizzle baked in)
template<bool SWZ>
__global__ void transpose_f32f16(const float* __restrict__ src, half_t* __restrict__ dst,
                                 int K, int N) {
  __shared__ float tile[32][33];
  int n0 = blockIdx.x * 32, k0 = blockIdx.y * 32;
  int tx = threadIdx.x, ty = threadIdx.y;
#pragma unroll
  for (int j = 0; j < 4; ++j)
    tile[ty + j*8][tx] = src[(size_t)(k0 + ty + j*8)*N + n0 + tx];
  __syncthreads();
#pragma unroll
  for (int j = 0; j < 4; ++j) {
    int n = n0 + ty + j*8, k = k0 + tx;
    size_t byte = ((size_t)n*K + k)*2;
    if (SWZ) byte ^= ((size_t)((n>>1)&3))<<4;
    *(half_t*)((char*)dst + byte) = (half_t)tile[tx][ty + j*8];
  }
}

__global__ void convert_pad_y(const float* __restrict__ y, half_t* __restrict__ yh) {
  int idx = blockIdx.x * 256 + threadIdx.x;
  int s = idx / D_CROSS;
  yh[idx] = (s < ROWS_KV) ? (half_t)y[idx] : (half_t)0.f;
}

__global__ void concat_bias(const float* __restrict__ bk, const float* __restrict__ bv,
                            float* __restrict__ bkv) {
  int i = blockIdx.x * 256 + threadIdx.x;
  bkv[i] = (i < D_EMBED) ? bk[i] : bv[i - D_EMBED];
}

// ---------------- small GEMM for K/V proj (old 128x128 structure, plain layouts) ----------------
__global__ __launch_bounds__(256, 2)
void gemm_f16_128(const half_t* __restrict__ A, const half_t* __restrict__ Bt,
                  const float* __restrict__ bias, half_t* __restrict__ C,
                  int M, int N, int K) {
  __shared__ half_t As[128*32];
  __shared__ half_t Bs[128*32];
  const int tid = threadIdx.x;
  const int l = tid & 63, w = tid >> 6;
  const int l4 = l & 15, lh = l >> 4;
  const int bn0 = blockIdx.x * 128, bm0 = blockIdx.y * 128;
  const int wr = w >> 1, wc = w & 1;
  f32x4 acc[4][4] = {};
  const int nk = K >> 5;
  for (int kt = 0; kt < nk; ++kt) {
    {
      const half_t* g0 = Bt + (size_t)(bn0 + w*16 + (l >> 2))*K + kt*32 + (l & 3)*8;
      gload_lds16(g0, (char*)Bs + w*1024);
      const half_t* g1 = Bt + (size_t)(bn0 + 64 + w*16 + (l >> 2))*K + kt*32 + (l & 3)*8;
      gload_lds16(g1, (char*)Bs + 4096 + w*1024);
      const half_t* a0 = A + (size_t)(bm0 + w*16 + (l >> 2))*K + kt*32 + (l & 3)*8;
      gload_lds16(a0, (char*)As + w*1024);
      const half_t* a1 = A + (size_t)(bm0 + 64 + w*16 + (l >> 2))*K + kt*32 + (l & 3)*8;
      gload_lds16(a1, (char*)As + 4096 + w*1024);
    }
    __syncthreads();
    half8 af[4], bf[4];
#pragma unroll
    for (int m = 0; m < 4; ++m)
      af[m] = *(const half8*)(As + (size_t)(wr*64 + m*16 + l4)*32 + lh*8);
#pragma unroll
    for (int n = 0; n < 4; ++n)
      bf[n] = *(const half8*)(Bs + (size_t)(wc*64 + n*16 + l4)*32 + lh*8);
#pragma unroll
    for (int m = 0; m < 4; ++m)
#pragma unroll
      for (int n = 0; n < 4; ++n)
        acc[m][n] = __builtin_amdgcn_mfma_f32_16x16x32_f16(af[m], bf[n], acc[m][n], 0, 0, 0);
    __syncthreads();
  }
  const int cb = bn0 + wc*64, rb = bm0 + wr*64;
#pragma unroll
  for (int n = 0; n < 4; ++n) {
    const int col = cb + n*16 + l4;
    const float bvv = bias[col];
#pragma unroll
    for (int m = 0; m < 4; ++m)
#pragma unroll
      for (int j = 0; j < 4; ++j)
        C[(size_t)(rb + m*16 + lh*4 + j)*N + col] = (half_t)(acc[m][j + 0 ? 0 : 0][0]*0.f + acc[m][n][j] + bvv);
  }
}

// ---------------- 256x256 deep-pipelined GEMM ----------------
// C[M,N] = A[M,K]*Bt[N,K]^T + bias. 512 thr = 8 waves (2M x 4N), wave tile 128x64.
// BK=32, LDS double-buffered 4x16KB. Counted vmcnt prefetch (1 K-tile ahead), raw barriers.
// LDS layout [256 rows][32 halfs], reads XOR-swizzled: byte ^= ((row>>1)&3)<<4.
// Bt (and A when fp16) are PRE-swizzled in global; staging copies verbatim (linear).
// AF32: A fp32 unswizzled; reg-load early, cvt+swizzled ds_write late (T14 split).
template<bool AF32, bool OUTF32>
__global__ __launch_bounds__(512, 2)
void gemm256(const void* __restrict__ Av, const half_t* __restrict__ Bt,
             const float* __restrict__ bias, void* __restrict__ Cv,
             int M, int N, int K) {
  __shared__ half_t As[2][256*32];
  __shared__ half_t Bs[2][256*32];
  const int tid = threadIdx.x;
  const int l = tid & 63, w = tid >> 6;
  const int l4 = l & 15, lh = l >> 4;
  // XCD panel-grouping (grid divisible by 8): same-XCD slots consecutive in lin
  const int s = blockIdx.x;
  const int lin = (s & 7) * ((int)gridDim.x >> 3) + (s >> 3);
  const int nbx = N >> 8;
  const int bx = lin % nbx, by = lin / nbx;
  const int bm0 = by << 8, bn0 = bx << 8;
  const int wr = w >> 2, wc = w & 3;

  f32x4 acc[8][4] = {};
  const int NT = K >> 5;

  const half_t* Bg = Bt + (size_t)(bn0 + (tid >> 2))*K + (tid & 3)*8;
  char* BsW0 = (char*)Bs[0] + (tid >> 6)*1024;   // wave-uniform LDS base (+8192 for round 1)
  char* AsW0 = (char*)As[0] + (tid >> 6)*1024;

  auto stageB = [&](int kt, int bb) {
    const half_t* g = Bg + kt*32;
    gload_lds16(g,                    BsW0 + (size_t)bb*16384);
    gload_lds16(g + (size_t)128*K,    BsW0 + (size_t)bb*16384 + 8192);
  };
  auto stageA16 = [&](int kt, int bb) {
    const half_t* A = (const half_t*)Av;
    const half_t* g = A + (size_t)(bm0 + (tid >> 2))*K + kt*32 + (tid & 3)*8;
    gload_lds16(g,                    AsW0 + (size_t)bb*16384);
    gload_lds16(g + (size_t)128*K,    AsW0 + (size_t)bb*16384 + 8192);
  };

  f32x4 Ld0, Ld1, Ld2, Ld3;                  // AF32 staging regs (16 VGPR)
  const float* Xg = AF32 ? ((const float*)Av + (size_t)(bm0 + (tid >> 1))*K + (tid & 1)*16) : nullptr;
  auto aload = [&](int kt) {
    const f32x4* g = (const f32x4*)(Xg + kt*32);
    Ld0 = g[0]; Ld1 = g[1]; Ld2 = g[2]; Ld3 = g[3];
  };
  auto awrite = [&](int bb) {
    const int row = tid >> 1;
    const int s0 = (tid & 1) * 2;
    const int key = (row >> 1) & 3;
    half8 h0, h1;
#pragma unroll
    for (int j = 0; j < 4; ++j) { h0[j] = (half_t)Ld0[j]; h0[j+4] = (half_t)Ld1[j]; }
#pragma unroll
    for (int j = 0; j < 4; ++j) { h1[j] = (half_t)Ld2[j]; h1[j+4] = (half_t)Ld3[j]; }
    char* base = (char*)As[bb] + row*64;
    *(half8*)(base + ((s0     ^ key) << 4)) = h0;
    *(half8*)(base + (((s0+1) ^ key) << 4)) = h1;
  };

  auto compute = [&](int bb) {
    const char* bsb = (const char*)Bs[bb];
    const char* asb = (const char*)As[bb];
    half8 bf[4];
#pragma unroll
    for (int ni = 0; ni < 4; ++ni) {
      const int row = wc*64 + ni*16 + l4;
      bf[ni] = *(const half8*)(bsb + row*64 + ((lh ^ ((row >> 1) & 3)) << 4));
    }
#pragma unroll
    for (int mi = 0; mi < 8; ++mi) {
      const int row = wr*128 + mi*16 + l4;
      half8 af = *(const half8*)(asb + row*64 + ((lh ^ ((row >> 1) & 3)) << 4));
      __builtin_amdgcn_s_setprio(1);
#pragma unroll
      for (int ni = 0; ni < 4; ++ni)
        acc[mi][ni] = __builtin_amdgcn_mfma_f32_16x16x32_f16(af, bf[ni], acc[mi][ni], 0, 0, 0);
      __builtin_amdgcn_s_setprio(0);
    }
  };

  if constexpr (!AF32) {
    stageA16(0, 0); stageB(0, 0);
    for (int t = 0; t < NT - 1; ++t) {
      stageA16(t+1, (t+1) & 1); stageB(t+1, (t+1) & 1);
      asm volatile("s_waitcnt vmcnt(4)" ::: "memory");
      __builtin_amdgcn_sched_barrier(0);
      BAR();
      compute(t & 1);
      BAR();
    }
    asm volatile("s_waitcnt vmcnt(0)" ::: "memory");
    __builtin_amdgcn_sched_barrier(0);
    BAR();
    compute((NT-1) & 1);
  } else {
    aload(0); stageB(0, 0);
    awrite(0);                                     // auto-waits the 4 A loads
    asm volatile("s_waitcnt vmcnt(0) lgkmcnt(0)" ::: "memory");
    __builtin_amdgcn_sched_barrier(0);
    BAR();
    for (int t = 0; t < NT; ++t) {
      if (t < NT - 1) {
        aload(t+1); stageB(t+1, (t+1) & 1);        // issue early (T14)
        __builtin_amdgcn_sched_barrier(0);         // pin issue before compute
      }
      compute(t & 1);
      if (t < NT - 1) {
        awrite((t+1) & 1);                         // cvt + swizzled ds_write (late)
        asm volatile("s_waitcnt vmcnt(0) lgkmcnt(0)" ::: "memory");
        __builtin_amdgcn_sched_barrier(0);
      }
      BAR();
    }
  }

  // epilogue: row = bm0+wr*128+mi*16+lh*4+j, col = bn0+wc*64+ni*16+l4
  const int cb = bn0 + wc*64;
  const int rb = bm0 + wr*128;
#pragma unroll
  for (int ni = 0; ni < 4; ++ni) {
    const int col = cb + ni*16 + l4;
    const float bvv = bias[col];
#pragma unroll
    for (int mi = 0; mi < 8; ++mi) {
#pragma unroll
      for (int j = 0; j < 4; ++j) {
        const int row = rb + mi*16 + lh*4 + j;
        const float v = acc[mi][ni][j] + bvv;
        if constexpr (OUTF32) {
          ((float*)Cv)[(size_t)row*N + col] = v;
        } else {
          size_t byte = ((size_t)row*N + col)*2;
          byte ^= ((size_t)((row >> 1) & 3)) << 4;  // store q swizzled
          *(half_t*)((char*)Cv + byte) = (half_t)v;
        }
      }
    }
  }
}

// ---------------- attention ----------------
// q is SWIZZLED fp16 (XOR byte[5:4] with (row>>1)&3); kv plain.
__global__ __launch_bounds__(256, 2)
void attn_kernel(half_t* __restrict__ q, const half_t* __restrict__ kv) {
  __shared__ half_t K_lds[80*136];
  __shared__ half_t Vt_lds[128*104];
  __shared__ half_t P_lds[64*104];
  const int tid = threadIdx.x;
  const int l = tid & 63, w = tid >> 6;
  const int l4 = l & 15, lh = l >> 4;
  const int bh = blockIdx.y;
  const int b = bh >> 3, h = bh & 7;
  const size_t kvbase = (size_t)b*SEQ_KV*2048 + (size_t)h*D_HEAD;

  for (int i = tid; i < 80*16; i += 256) {
    int s = i >> 4, d = (i & 15) << 3;
    half8 v = {};
    if (s < SEQ_KV) v = *(const half8*)(kv + kvbase + (size_t)s*2048 + d);
    *(half8*)(K_lds + s*136 + d) = v;
  }
  for (int i = tid; i < 96*16; i += 256) {
    int s = i >> 4, d = (i & 15) << 3;
    half8 v = {};
    if (s < SEQ_KV) v = *(const half8*)(kv + kvbase + (size_t)s*2048 + 1024 + d);
#pragma unroll
    for (int j = 0; j < 8; ++j) Vt_lds[(size_t)(d + j)*104 + s] = v[j];
  }
  {
    int rr = tid >> 2, cc = 80 + (tid & 3)*4;
    *reinterpret_cast<uint2*>(P_lds + (size_t)rr*104 + cc) = make_uint2(0u, 0u);
  }
  __syncthreads();

  const int qrow0 = blockIdx.x*64 + w*16;
  const size_t qrow = (size_t)b*SEQ_Q + qrow0 + l4;
  const size_t rowbyte = qrow*2048;
  const size_t rkey = ((size_t)((l4 >> 1) & 3)) << 4;   // (qrow>>1)&3 == (l4>>1)&3
  half8 qf[4];
#pragma unroll
  for (int kk = 0; kk < 4; ++kk) {
    size_t byte = rowbyte + (size_t)h*256 + kk*64 + lh*16;
    qf[kk] = *(const half8*)((const char*)q + (byte ^ rkey));
  }

  f32x4 sa[5] = {};
#pragma unroll
  for (int nb = 0; nb < 5; ++nb)
#pragma unroll
    for (int kk = 0; kk < 4; ++kk) {
      half8 kf = *(const half8*)(K_lds + (size_t)(nb*16 + l4)*136 + kk*32 + lh*8);
      sa[nb] = __builtin_amdgcn_mfma_f32_16x16x32_f16(qf[kk], kf, sa[nb], 0, 0, 0);
    }

  const float scale = 0.08838834764831845f;
#pragma unroll
  for (int j = 0; j < 4; ++j) {
    float pv[5];
    float mx = -1e30f;
#pragma unroll
    for (int nb = 0; nb < 5; ++nb) {
      int col = nb*16 + l4;
      float sv = (col < SEQ_KV) ? sa[nb][j]*scale : -1e30f;
      pv[nb] = sv;
      mx = fmaxf(mx, sv);
    }
    mx = fmaxf(mx, __shfl_xor(mx, 1));
    mx = fmaxf(mx, __shfl_xor(mx, 2));
    mx = fmaxf(mx, __shfl_xor(mx, 4));
    mx = fmaxf(mx, __shfl_xor(mx, 8));
    float sm = 0.f;
#pragma unroll
    for (int nb = 0; nb < 5; ++nb) { float e = __expf(pv[nb] - mx); pv[nb] = e; sm += e; }
    sm += __shfl_xor(sm, 1);
    sm += __shfl_xor(sm, 2);
    sm += __shfl_xor(sm, 4);
    sm += __shfl_xor(sm, 8);
    const float inv = 1.f / sm;
    const int prow = w*16 + lh*4 + j;
#pragma unroll
    for (int nb = 0; nb < 5; ++nb)
      P_lds[(size_t)prow*104 + nb*16 + l4] = (half_t)(pv[nb]*inv);
  }

  half8 pf[3];
#pragma unroll
  for (int kk = 0; kk < 3; ++kk)
    pf[kk] = *(const half8*)(P_lds + (size_t)(w*16 + l4)*104 + kk*32 + lh*8);
  f32x4 oa[8] = {};
#pragma unroll
  for (int nd = 0; nd < 8; ++nd)
#pragma unroll
    for (int kk = 0; kk < 3; ++kk) {
      half8 vf = *(const half8*)(Vt_lds + (size_t)(nd*16 + l4)*104 + kk*32 + lh*8);
      oa[nd] = __builtin_amdgcn_mfma_f32_16x16x32_f16(pf[kk], vf, oa[nd], 0, 0, 0);
    }
  // write O in place, swizzled
#pragma unroll
  for (int nd = 0; nd < 8; ++nd) {
#pragma unroll
    for (int j = 0; j < 4; ++j) {
      const int rl = lh*4 + j;
      const size_t row = (size_t)b*SEQ_Q + qrow0 + rl;
      size_t byte = row*2048 + (size_t)h*256 + (size_t)(nd*16 + l4)*2;
      byte ^= ((size_t)((rl >> 1) & 3)) << 4;
      *(half_t*)((char*)q + byte) = (half_t)oa[nd][j];
    }
  }
}

// ---------------- launch ----------------
extern "C" void kernel_launch(void* const* d_in, const int* in_sizes, int n_in,
                              void* d_out, int out_size, void* d_ws, size_t ws_size,
                              hipStream_t stream) {
  (void)in_sizes; (void)n_in; (void)out_size; (void)ws_size;
  const float* x  = (const float*)d_in[0];
  const float* y  = (const float*)d_in[1];
  const float* Wq = (const float*)d_in[2];
  const float* bq = (const float*)d_in[3];
  const float* Wk = (const float*)d_in[4];
  const float* bk = (const float*)d_in[5];
  const float* Wv = (const float*)d_in[6];
  const float* bv = (const float*)d_in[7];
  const float* Wo = (const float*)d_in[8];
  const float* bo = (const float*)d_in[9];

  char* ws = (char*)d_ws;
  half_t* q    = (half_t*)(ws + WS_Q);
  half_t* Wqt  = (half_t*)(ws + WS_WQT);
  half_t* Wot  = (half_t*)(ws + WS_WOT);
  half_t* Wkvt = (half_t*)(ws + WS_WKVT);
  half_t* yh   = (half_t*)(ws + WS_YH);
  half_t* kvb  = (half_t*)(ws + WS_KV);
  float*  bkv  = (float*)(ws + WS_BKV);

  dim3 tb(32, 8);
  transpose_f32f16<true ><<<dim3(32, 32), tb, 0, stream>>>(Wq, Wqt, 1024, 1024);
  transpose_f32f16<true ><<<dim3(32, 32), tb, 0, stream>>>(Wo, Wot, 1024, 1024);
  transpose_f32f16<false><<<dim3(32, 24), tb, 0, stream>>>(Wk, Wkvt, 768, 1024);
  transpose_f32f16<false><<<dim3(32, 24), tb, 0, stream>>>(Wv, Wkvt + (size_t)1024*768, 768, 1024);
  convert_pad_y<<<ROWS_KV_PAD*D_CROSS/256, 256, 0, stream>>>(y, yh);
  concat_bias<<<2*D_EMBED/256, 256, 0, stream>>>(bk, bv, bkv);

  // K/V projection: [640,768] @ [768,2048] (plain layouts)
  gemm_f16_128<<<dim3(16, 5), 256, 0, stream>>>(yh, Wkvt, bkv, kvb, ROWS_KV_PAD, 2048, 768);
  // Q projection: fp32 A fused, 256^2 pipelined -> q (swizzled fp16)
  gemm256<true, false><<<512, 512, 0, stream>>>(x, Wqt, bq, q, M_Q, 1024, 1024);
  // attention (in-place over swizzled q)
  attn_kernel<<<dim3(64, 64), 256, 0, stream>>>(q, kvb);
  // O projection: fp16 A (swizzled q), 256^2 pipelined -> fp32 d_out
  gemm256<false, true><<<512, 512, 0, stream>>>(q, Wot, bo, (float*)d_out, M_Q, 1024, 1024);
}

// Round 4
// 348.791 us; speedup vs baseline: 1.0872x; 1.0872x over previous
//
#include <hip/hip_runtime.h>

typedef _Float16 half_t;
typedef _Float16 half8 __attribute__((ext_vector_type(8)));
typedef float f32x4 __attribute__((ext_vector_type(4)));

#define D_EMBED   1024
#define D_CROSS   768
#define N_HEADS   8
#define D_HEAD    128
#define BATCH     8
#define SEQ_Q     4096
#define SEQ_KV    77
#define M_Q       (BATCH*SEQ_Q)     /* 32768 */
#define ROWS_KV   (BATCH*SEQ_KV)    /* 616   */
#define ROWS_KV_PAD 640

// ---------------- workspace layout (bytes) ----------------
#define WS_Q     ((size_t)0)                                  // q (swizzled fp16), attn-out in place
#define WS_WQT   (WS_Q    + (size_t)M_Q*D_EMBED*2)            // Wq^T fp16 [1024][1024] swizzled
#define WS_WOT   (WS_WQT  + (size_t)D_EMBED*D_EMBED*2)        // Wo^T fp16 [1024][1024] swizzled
#define WS_WKVT  (WS_WOT  + (size_t)D_EMBED*D_EMBED*2)        // [Wk;Wv]^T fp16 [2048][768] plain
#define WS_YH    (WS_WKVT + (size_t)2*D_EMBED*D_CROSS*2)      // y fp16 padded [640][768]
#define WS_KV    (WS_YH   + (size_t)ROWS_KV_PAD*D_CROSS*2)    // kv fp16 [640][2048] plain
#define WS_BKV   (WS_KV   + (size_t)ROWS_KV_PAD*2*D_EMBED*2)  // bias concat fp32 [2048]

__device__ __forceinline__ void gload_lds16(const void* g, void* lds) {
  __builtin_amdgcn_global_load_lds(
      (const __attribute__((address_space(1))) unsigned int*)g,
      (__attribute__((address_space(3))) unsigned int*)lds, 16, 0, 0);
}

// ---------------- prep kernels ----------------
// dst[n][k] = (half) src[k][n]; SWZ: XOR byte bits[5:4] with (n>>1)&3 (LDS bank swizzle baked in)
template<bool SWZ>
__global__ void transpose_f32f16(const float* __restrict__ src, half_t* __restrict__ dst,
                                 int K, int N) {
  __shared__ float tile[32][33];
  int n0 = blockIdx.x * 32, k0 = blockIdx.y * 32;
  int tx = threadIdx.x, ty = threadIdx.y;
#pragma unroll
  for (int j = 0; j < 4; ++j)
    tile[ty + j*8][tx] = src[(size_t)(k0 + ty + j*8)*N + n0 + tx];
  __syncthreads();
#pragma unroll
  for (int j = 0; j < 4; ++j) {
    int n = n0 + ty + j*8, k = k0 + tx;
    size_t byte = ((size_t)n*K + k)*2;
    if (SWZ) byte ^= ((size_t)((n>>1)&3))<<4;
    *(half_t*)((char*)dst + byte) = (half_t)tile[tx][ty + j*8];
  }
}

__global__ void convert_pad_y(const float* __restrict__ y, half_t* __restrict__ yh) {
  int idx = blockIdx.x * 256 + threadIdx.x;
  int s = idx / D_CROSS;
  yh[idx] = (s < ROWS_KV) ? (half_t)y[idx] : (half_t)0.f;
}

__global__ void concat_bias(const float* __restrict__ bk, const float* __restrict__ bv,
                            float* __restrict__ bkv) {
  int i = blockIdx.x * 256 + threadIdx.x;
  bkv[i] = (i < D_EMBED) ? bk[i] : bv[i - D_EMBED];
}

// ---------------- GEMM: C[M,N] = A[M,K] * Bt[N,K]^T + bias[N] ----------------
// R2-proven structure: 128x128 tile, BK=32, 256 thr (4 waves), wave tile 64x64,
// __syncthreads 2-phase loop, global_load_lds staging, compiler scheduling.
// SWZ adds ONLY: (a) XCD panel-coherent block remap (needs gridDim.x==8);
// (b) LDS bank swizzle: globals pre-swizzled (byte^=((row>>1)&3)<<4, within 64B
//     groups), staging copies linear, ds_read/ds_write XOR the 16B slot.
//     XOR key is a per-lane constant -> zero VALU in the K loop.
// AF32: A fp32 in global (unswizzled), reg-stage + cvt + (swizzled) ds_write.
template<bool AF32, bool OUTF32, bool SWZ>
__global__ __launch_bounds__(256, 2)
void gemm_f16(const void* __restrict__ Av, const half_t* __restrict__ Bt,
              const float* __restrict__ bias, void* __restrict__ Cv,
              int M, int N, int K) {
  __shared__ half_t As[128*32];
  __shared__ half_t Bs[128*32];
  const int tid = threadIdx.x;
  const int l  = tid & 63;
  const int w  = tid >> 6;
  const int l4 = l & 15, lh = l >> 4;

  int bx, by;
  if constexpr (SWZ) {
    const int s = blockIdx.x + (blockIdx.y << 3);
    bx = (s >> 3) & 7;
    by = (s & 7) + ((s >> 6) << 3);
  } else {
    bx = blockIdx.x; by = blockIdx.y;
  }
  const int bn0 = bx * 128;
  const int bm0 = by * 128;
  const int wr = w >> 1, wc = w & 1;
  // compute-read slot key: row bits[2:1] come only from l4 (wr*64, m*16 contribute 0)
  const int skey = SWZ ? ((l4 >> 1) & 3) : 0;
  const int rslot = (lh ^ skey) << 4;      // byte offset of 16B slot within 64B row

  f32x4 acc[4][4] = {};
  const int nk = K >> 5;

  for (int kt = 0; kt < nk; ++kt) {
    // ---- stage B (fp16, linear copy of pre-swizzled global) ----
    {
      const half_t* g0 = Bt + (size_t)(bn0 + w*16 + (l >> 2))*K + kt*32 + (l & 3)*8;
      gload_lds16(g0, (char*)Bs + w*1024);
      const half_t* g1 = Bt + (size_t)(bn0 + 64 + w*16 + (l >> 2))*K + kt*32 + (l & 3)*8;
      gload_lds16(g1, (char*)Bs + 4096 + w*1024);
    }
    // ---- stage A ----
    if constexpr (!AF32) {
      const half_t* A = (const half_t*)Av;
      const half_t* g0 = A + (size_t)(bm0 + w*16 + (l >> 2))*K + kt*32 + (l & 3)*8;
      gload_lds16(g0, (char*)As + w*1024);
      const half_t* g1 = A + (size_t)(bm0 + 64 + w*16 + (l >> 2))*K + kt*32 + (l & 3)*8;
      gload_lds16(g1, (char*)As + 4096 + w*1024);
    } else {
      const float* A = (const float*)Av;
      const int row = tid >> 2;                    // 0..63
      const int wslot = SWZ ? (((tid & 3) ^ ((tid >> 3) & 3)) << 4)   // key=(row>>1)&3=(tid>>3)&3
                            : ((tid & 3) << 4);
#pragma unroll
      for (int r = 0; r < 2; ++r) {
        const float* g = A + (size_t)(bm0 + r*64 + row)*K + kt*32 + (tid & 3)*8;
        f32x4 f0 = *(const f32x4*)g;
        f32x4 f1 = *(const f32x4*)(g + 4);
        half8 hv;
        hv[0]=(half_t)f0[0]; hv[1]=(half_t)f0[1]; hv[2]=(half_t)f0[2]; hv[3]=(half_t)f0[3];
        hv[4]=(half_t)f1[0]; hv[5]=(half_t)f1[1]; hv[6]=(half_t)f1[2]; hv[7]=(half_t)f1[3];
        *(half8*)((char*)As + (size_t)(r*64 + row)*64 + wslot) = hv;
      }
    }
    __syncthreads();
    // ---- compute ----
    half8 af[4], bf[4];
#pragma unroll
    for (int m = 0; m < 4; ++m)
      af[m] = *(const half8*)((const char*)As + (size_t)(wr*64 + m*16 + l4)*64 + rslot);
#pragma unroll
    for (int n = 0; n < 4; ++n)
      bf[n] = *(const half8*)((const char*)Bs + (size_t)(wc*64 + n*16 + l4)*64 + rslot);
#pragma unroll
    for (int m = 0; m < 4; ++m)
#pragma unroll
      for (int n = 0; n < 4; ++n)
        acc[m][n] = __builtin_amdgcn_mfma_f32_16x16x32_f16(af[m], bf[n], acc[m][n], 0, 0, 0);
    __syncthreads();
  }

  // ---- epilogue: row = bm0+wr*64+m*16+lh*4+j, col = bn0+wc*64+n*16+l4 ----
  const int c_base = bn0 + wc*64;
  const int r_base = bm0 + wr*64;
#pragma unroll
  for (int n = 0; n < 4; ++n) {
    const int col = c_base + n*16 + l4;
    const float bvv = bias[col];
#pragma unroll
    for (int m = 0; m < 4; ++m) {
#pragma unroll
      for (int j = 0; j < 4; ++j) {
        const int row = r_base + m*16 + lh*4 + j;
        const float v = acc[m][n][j] + bvv;
        if constexpr (OUTF32) {
          ((float*)Cv)[(size_t)row*N + col] = v;
        } else if constexpr (SWZ) {
          size_t byte = ((size_t)row*N + col)*2;
          byte ^= ((size_t)((row >> 1) & 3)) << 4;       // store q pre-swizzled
          *(half_t*)((char*)Cv + byte) = (half_t)v;
        } else {
          ((half_t*)Cv)[(size_t)row*N + col] = (half_t)v;
        }
      }
    }
  }
}

// ---------------- attention ----------------
// q is SWIZZLED fp16 (XOR byte[5:4] with (row>>1)&3); kv plain. (Verified R3.)
__global__ __launch_bounds__(256, 2)
void attn_kernel(half_t* __restrict__ q, const half_t* __restrict__ kv) {
  __shared__ half_t K_lds[80*136];
  __shared__ half_t Vt_lds[128*104];
  __shared__ half_t P_lds[64*104];
  const int tid = threadIdx.x;
  const int l = tid & 63, w = tid >> 6;
  const int l4 = l & 15, lh = l >> 4;
  const int bh = blockIdx.y;
  const int b = bh >> 3, h = bh & 7;
  const size_t kvbase = (size_t)b*SEQ_KV*2048 + (size_t)h*D_HEAD;

  for (int i = tid; i < 80*16; i += 256) {
    int s = i >> 4, d = (i & 15) << 3;
    half8 v = {};
    if (s < SEQ_KV) v = *(const half8*)(kv + kvbase + (size_t)s*2048 + d);
    *(half8*)(K_lds + s*136 + d) = v;
  }
  for (int i = tid; i < 96*16; i += 256) {
    int s = i >> 4, d = (i & 15) << 3;
    half8 v = {};
    if (s < SEQ_KV) v = *(const half8*)(kv + kvbase + (size_t)s*2048 + 1024 + d);
#pragma unroll
    for (int j = 0; j < 8; ++j) Vt_lds[(size_t)(d + j)*104 + s] = v[j];
  }
  {
    int rr = tid >> 2, cc = 80 + (tid & 3)*4;
    *reinterpret_cast<uint2*>(P_lds + (size_t)rr*104 + cc) = make_uint2(0u, 0u);
  }
  __syncthreads();

  const int qrow0 = blockIdx.x*64 + w*16;
  const size_t qrow = (size_t)b*SEQ_Q + qrow0 + l4;
  const size_t rowbyte = qrow*2048;
  const size_t rkey = ((size_t)((l4 >> 1) & 3)) << 4;   // (qrow>>1)&3 == (l4>>1)&3
  half8 qf[4];
#pragma unroll
  for (int kk = 0; kk < 4; ++kk) {
    size_t byte = rowbyte + (size_t)h*256 + kk*64 + lh*16;
    qf[kk] = *(const half8*)((const char*)q + (byte ^ rkey));
  }

  f32x4 sa[5] = {};
#pragma unroll
  for (int nb = 0; nb < 5; ++nb)
#pragma unroll
    for (int kk = 0; kk < 4; ++kk) {
      half8 kf = *(const half8*)(K_lds + (size_t)(nb*16 + l4)*136 + kk*32 + lh*8);
      sa[nb] = __builtin_amdgcn_mfma_f32_16x16x32_f16(qf[kk], kf, sa[nb], 0, 0, 0);
    }

  const float scale = 0.08838834764831845f;
#pragma unroll
  for (int j = 0; j < 4; ++j) {
    float pv[5];
    float mx = -1e30f;
#pragma unroll
    for (int nb = 0; nb < 5; ++nb) {
      int col = nb*16 + l4;
      float sv = (col < SEQ_KV) ? sa[nb][j]*scale : -1e30f;
      pv[nb] = sv;
      mx = fmaxf(mx, sv);
    }
    mx = fmaxf(mx, __shfl_xor(mx, 1));
    mx = fmaxf(mx, __shfl_xor(mx, 2));
    mx = fmaxf(mx, __shfl_xor(mx, 4));
    mx = fmaxf(mx, __shfl_xor(mx, 8));
    float sm = 0.f;
#pragma unroll
    for (int nb = 0; nb < 5; ++nb) { float e = __expf(pv[nb] - mx); pv[nb] = e; sm += e; }
    sm += __shfl_xor(sm, 1);
    sm += __shfl_xor(sm, 2);
    sm += __shfl_xor(sm, 4);
    sm += __shfl_xor(sm, 8);
    const float inv = 1.f / sm;
    const int prow = w*16 + lh*4 + j;
#pragma unroll
    for (int nb = 0; nb < 5; ++nb)
      P_lds[(size_t)prow*104 + nb*16 + l4] = (half_t)(pv[nb]*inv);
  }

  half8 pf[3];
#pragma unroll
  for (int kk = 0; kk < 3; ++kk)
    pf[kk] = *(const half8*)(P_lds + (size_t)(w*16 + l4)*104 + kk*32 + lh*8);
  f32x4 oa[8] = {};
#pragma unroll
  for (int nd = 0; nd < 8; ++nd)
#pragma unroll
    for (int kk = 0; kk < 3; ++kk) {
      half8 vf = *(const half8*)(Vt_lds + (size_t)(nd*16 + l4)*104 + kk*32 + lh*8);
      oa[nd] = __builtin_amdgcn_mfma_f32_16x16x32_f16(pf[kk], vf, oa[nd], 0, 0, 0);
    }
  // write O in place, swizzled
#pragma unroll
  for (int nd = 0; nd < 8; ++nd) {
#pragma unroll
    for (int j = 0; j < 4; ++j) {
      const int rl = lh*4 + j;
      const size_t row = (size_t)b*SEQ_Q + qrow0 + rl;
      size_t byte = row*2048 + (size_t)h*256 + (size_t)(nd*16 + l4)*2;
      byte ^= ((size_t)((rl >> 1) & 3)) << 4;
      *(half_t*)((char*)q + byte) = (half_t)oa[nd][j];
    }
  }
}

// ---------------- launch ----------------
extern "C" void kernel_launch(void* const* d_in, const int* in_sizes, int n_in,
                              void* d_out, int out_size, void* d_ws, size_t ws_size,
                              hipStream_t stream) {
  (void)in_sizes; (void)n_in; (void)out_size; (void)ws_size;
  const float* x  = (const float*)d_in[0];
  const float* y  = (const float*)d_in[1];
  const float* Wq = (const float*)d_in[2];
  const float* bq = (const float*)d_in[3];
  const float* Wk = (const float*)d_in[4];
  const float* bk = (const float*)d_in[5];
  const float* Wv = (const float*)d_in[6];
  const float* bv = (const float*)d_in[7];
  const float* Wo = (const float*)d_in[8];
  const float* bo = (const float*)d_in[9];

  char* ws = (char*)d_ws;
  half_t* q    = (half_t*)(ws + WS_Q);
  half_t* Wqt  = (half_t*)(ws + WS_WQT);
  half_t* Wot  = (half_t*)(ws + WS_WOT);
  half_t* Wkvt = (half_t*)(ws + WS_WKVT);
  half_t* yh   = (half_t*)(ws + WS_YH);
  half_t* kvb  = (half_t*)(ws + WS_KV);
  float*  bkv  = (float*)(ws + WS_BKV);

  dim3 tb(32, 8);
  transpose_f32f16<true ><<<dim3(32, 32), tb, 0, stream>>>(Wq, Wqt, 1024, 1024);
  transpose_f32f16<true ><<<dim3(32, 32), tb, 0, stream>>>(Wo, Wot, 1024, 1024);
  transpose_f32f16<false><<<dim3(32, 24), tb, 0, stream>>>(Wk, Wkvt, 768, 1024);
  transpose_f32f16<false><<<dim3(32, 24), tb, 0, stream>>>(Wv, Wkvt + (size_t)1024*768, 768, 1024);
  convert_pad_y<<<ROWS_KV_PAD*D_CROSS/256, 256, 0, stream>>>(y, yh);
  concat_bias<<<2*D_EMBED/256, 256, 0, stream>>>(bk, bv, bkv);

  // K/V projection: [640,768] @ [768,2048] (plain layouts)
  gemm_f16<false, false, false><<<dim3(16, 5), 256, 0, stream>>>(yh, Wkvt, bkv, kvb, ROWS_KV_PAD, 2048, 768);
  // Q projection: fp32 A fused, bank-swizzled LDS, XCD panel swizzle -> q (swizzled fp16)
  gemm_f16<true, false, true><<<dim3(8, 256), 256, 0, stream>>>(x, Wqt, bq, q, M_Q, 1024, 1024);
  // attention (in-place over swizzled q)
  attn_kernel<<<dim3(64, 64), 256, 0, stream>>>(q, kvb);
  // O projection: fp16 A (swizzled q), bank-swizzled LDS -> fp32 d_out
  gemm_f16<false, true, true><<<dim3(8, 256), 256, 0, stream>>>(q, Wot, bo, (float*)d_out, M_Q, 1024, 1024);
}

// Round 5
// 343.817 us; speedup vs baseline: 1.1029x; 1.0145x over previous
//
#include <hip/hip_runtime.h>

typedef _Float16 half_t;
typedef _Float16 half8 __attribute__((ext_vector_type(8)));
typedef float f32x4 __attribute__((ext_vector_type(4)));

#define D_EMBED   1024
#define D_CROSS   768
#define N_HEADS   8
#define D_HEAD    128
#define BATCH     8
#define SEQ_Q     4096
#define SEQ_KV    77
#define M_Q       (BATCH*SEQ_Q)     /* 32768 */
#define ROWS_KV   (BATCH*SEQ_KV)    /* 616   */
#define ROWS_KV_PAD 640

// ---------------- workspace layout (bytes) ----------------
#define WS_Q     ((size_t)0)                                  // q (swizzled fp16), attn-out in place
#define WS_WQT   (WS_Q    + (size_t)M_Q*D_EMBED*2)            // Wq^T fp16 [1024][1024] swizzled
#define WS_WOT   (WS_WQT  + (size_t)D_EMBED*D_EMBED*2)        // Wo^T fp16 [1024][1024] swizzled
#define WS_WKVT  (WS_WOT  + (size_t)D_EMBED*D_EMBED*2)        // [Wk;Wv]^T fp16 [2048][768] plain
#define WS_YH    (WS_WKVT + (size_t)2*D_EMBED*D_CROSS*2)      // y fp16 padded [640][768]
#define WS_KV    (WS_YH   + (size_t)ROWS_KV_PAD*D_CROSS*2)    // kv fp16 [640][2048] plain
#define WS_BKV   (WS_KV   + (size_t)ROWS_KV_PAD*2*D_EMBED*2)  // bias concat fp32 [2048]

__device__ __forceinline__ void gload_lds16(const void* g, void* lds) {
  __builtin_amdgcn_global_load_lds(
      (const __attribute__((address_space(1))) unsigned int*)g,
      (__attribute__((address_space(3))) unsigned int*)lds, 16, 0, 0);
}

// ---------------- prep kernels ----------------
// dst[n][k] = (half) src[k][n]; SWZ: XOR byte bits[5:4] with (n>>1)&3 (LDS bank swizzle baked in)
template<bool SWZ>
__global__ void transpose_f32f16(const float* __restrict__ src, half_t* __restrict__ dst,
                                 int K, int N) {
  __shared__ float tile[32][33];
  int n0 = blockIdx.x * 32, k0 = blockIdx.y * 32;
  int tx = threadIdx.x, ty = threadIdx.y;
#pragma unroll
  for (int j = 0; j < 4; ++j)
    tile[ty + j*8][tx] = src[(size_t)(k0 + ty + j*8)*N + n0 + tx];
  __syncthreads();
#pragma unroll
  for (int j = 0; j < 4; ++j) {
    int n = n0 + ty + j*8, k = k0 + tx;
    size_t byte = ((size_t)n*K + k)*2;
    if (SWZ) byte ^= ((size_t)((n>>1)&3))<<4;
    *(half_t*)((char*)dst + byte) = (half_t)tile[tx][ty + j*8];
  }
}

__global__ void convert_pad_y(const float* __restrict__ y, half_t* __restrict__ yh) {
  int idx = blockIdx.x * 256 + threadIdx.x;
  int s = idx / D_CROSS;
  yh[idx] = (s < ROWS_KV) ? (half_t)y[idx] : (half_t)0.f;
}

__global__ void concat_bias(const float* __restrict__ bk, const float* __restrict__ bv,
                            float* __restrict__ bkv) {
  int i = blockIdx.x * 256 + threadIdx.x;
  bkv[i] = (i < D_EMBED) ? bk[i] : bv[i - D_EMBED];
}

// ---------------- GEMM: C[M,N] = A[M,K] * Bt[N,K]^T + bias[N] ----------------
// 128x128 tile, BK=32, 256 thr (4 waves), wave tile 64x64.
// THIS ROUND: double-buffered prefetch (T3 minimum 2-phase): STAGE(t+1) issued
// BEFORE compute(t); the iter-ending __syncthreads (vmcnt0+lgkm0) waits on loads
// that had the whole compute phase to land. AF32 = T14 split (loads early,
// cvt+ds_write after compute). Compiler owns all waitcnts (no hand asm).
// SWZ: XCD panel remap (gridDim.x==8) + LDS bank swizzle via pre-swizzled
// globals (byte^=((row>>1)&3)<<4), linear staging, XOR'd ds accesses.
template<bool AF32, bool OUTF32, bool SWZ>
__global__ __launch_bounds__(256, 2)
void gemm_f16(const void* __restrict__ Av, const half_t* __restrict__ Bt,
              const float* __restrict__ bias, void* __restrict__ Cv,
              int M, int N, int K) {
  __shared__ half_t As[2][128*32];
  __shared__ half_t Bs[2][128*32];
  const int tid = threadIdx.x;
  const int l  = tid & 63;
  const int w  = tid >> 6;
  const int l4 = l & 15, lh = l >> 4;

  int bx, by;
  if constexpr (SWZ) {
    const int s = blockIdx.x + (blockIdx.y << 3);
    bx = (s >> 3) & 7;
    by = (s & 7) + ((s >> 6) << 3);
  } else {
    bx = blockIdx.x; by = blockIdx.y;
  }
  const int bn0 = bx * 128;
  const int bm0 = by * 128;
  const int wr = w >> 1, wc = w & 1;
  const int skey = SWZ ? ((l4 >> 1) & 3) : 0;
  const int rslot = (lh ^ skey) << 4;      // byte offset of 16B slot within 64B row

  f32x4 acc[4][4] = {};
  const int nk = K >> 5;

  // staging address pieces (constant across iters)
  const int srow = w*16 + (l >> 2);        // 0..63
  const int scol = (l & 3)*8;              // half-elem col within 32
  const size_t bgoff0 = (size_t)(bn0 + srow)*K + scol;
  const size_t bgoff1 = (size_t)(bn0 + 64 + srow)*K + scol;

  auto stageB = [&](int kt, int bb) {
    gload_lds16(Bt + bgoff0 + kt*32, (char*)Bs[bb] + w*1024);
    gload_lds16(Bt + bgoff1 + kt*32, (char*)Bs[bb] + 4096 + w*1024);
  };
  auto stageA16 = [&](int kt, int bb) {
    const half_t* A = (const half_t*)Av;
    gload_lds16(A + (size_t)(bm0 + srow)*K + scol + kt*32,      (char*)As[bb] + w*1024);
    gload_lds16(A + (size_t)(bm0 + 64 + srow)*K + scol + kt*32, (char*)As[bb] + 4096 + w*1024);
  };

  // AF32 reg staging: row = tid>>2 (0..63), 8 floats/thread/row-half
  f32x4 L0, L1, L2, L3;                     // 16 VGPR in flight
  const int arow = tid >> 2;
  const int ac0  = (tid & 3) * 8;
  const int wslot = SWZ ? (((tid & 3) ^ ((tid >> 3) & 3)) << 4)   // key=(arow>>1)&3=(tid>>3)&3
                        : ((tid & 3) << 4);
  auto aload = [&](int kt) {
    const float* A = (const float*)Av;
    const float* g0 = A + (size_t)(bm0 + arow)*K + kt*32 + ac0;
    const float* g1 = A + (size_t)(bm0 + 64 + arow)*K + kt*32 + ac0;
    L0 = *(const f32x4*)g0; L1 = *(const f32x4*)(g0 + 4);
    L2 = *(const f32x4*)g1; L3 = *(const f32x4*)(g1 + 4);
  };
  auto awrite = [&](int bb) {
    half8 h0, h1;
#pragma unroll
    for (int j = 0; j < 4; ++j) { h0[j] = (half_t)L0[j]; h0[j+4] = (half_t)L1[j]; }
#pragma unroll
    for (int j = 0; j < 4; ++j) { h1[j] = (half_t)L2[j]; h1[j+4] = (half_t)L3[j]; }
    *(half8*)((char*)As[bb] + (size_t)arow*64 + wslot)        = h0;
    *(half8*)((char*)As[bb] + (size_t)(64 + arow)*64 + wslot) = h1;
  };

  auto compute = [&](int bb) {
    half8 af[4], bf[4];
#pragma unroll
    for (int m = 0; m < 4; ++m)
      af[m] = *(const half8*)((const char*)As[bb] + (size_t)(wr*64 + m*16 + l4)*64 + rslot);
#pragma unroll
    for (int n = 0; n < 4; ++n)
      bf[n] = *(const half8*)((const char*)Bs[bb] + (size_t)(wc*64 + n*16 + l4)*64 + rslot);
#pragma unroll
    for (int m = 0; m < 4; ++m)
#pragma unroll
      for (int n = 0; n < 4; ++n)
        acc[m][n] = __builtin_amdgcn_mfma_f32_16x16x32_f16(af[m], bf[n], acc[m][n], 0, 0, 0);
  };

  // ---- prologue: stage tile 0 into buf 0 ----
  if constexpr (AF32) {
    aload(0); stageB(0, 0); awrite(0);
  } else {
    stageA16(0, 0); stageB(0, 0);
  }
  __syncthreads();

  // ---- main loop: prefetch t+1 into buf^1, compute t, sync ----
  for (int t = 0; t < nk; ++t) {
    const int cur = t & 1, nb = cur ^ 1;
    if constexpr (AF32) {
      if (t + 1 < nk) { aload(t + 1); stageB(t + 1, nb); }
      compute(cur);
      if (t + 1 < nk) awrite(nb);      // loads landed during compute
    } else {
      if (t + 1 < nk) { stageA16(t + 1, nb); stageB(t + 1, nb); }
      compute(cur);
    }
    __syncthreads();                   // drains prefetch (vmcnt0) + lgkm
  }

  // ---- epilogue: row = bm0+wr*64+m*16+lh*4+j, col = bn0+wc*64+n*16+l4 ----
  const int c_base = bn0 + wc*64;
  const int r_base = bm0 + wr*64;
#pragma unroll
  for (int n = 0; n < 4; ++n) {
    const int col = c_base + n*16 + l4;
    const float bvv = bias[col];
#pragma unroll
    for (int m = 0; m < 4; ++m) {
#pragma unroll
      for (int j = 0; j < 4; ++j) {
        const int row = r_base + m*16 + lh*4 + j;
        const float v = acc[m][n][j] + bvv;
        if constexpr (OUTF32) {
          ((float*)Cv)[(size_t)row*N + col] = v;
        } else if constexpr (SWZ) {
          size_t byte = ((size_t)row*N + col)*2;
          byte ^= ((size_t)((row >> 1) & 3)) << 4;       // store q pre-swizzled
          *(half_t*)((char*)Cv + byte) = (half_t)v;
        } else {
          ((half_t*)Cv)[(size_t)row*N + col] = (half_t)v;
        }
      }
    }
  }
}

// ---------------- attention ----------------
// q is SWIZZLED fp16 (XOR byte[5:4] with (row>>1)&3); kv plain. (Verified R3/R4.)
__global__ __launch_bounds__(256, 2)
void attn_kernel(half_t* __restrict__ q, const half_t* __restrict__ kv) {
  __shared__ half_t K_lds[80*136];
  __shared__ half_t Vt_lds[128*104];
  __shared__ half_t P_lds[64*104];
  const int tid = threadIdx.x;
  const int l = tid & 63, w = tid >> 6;
  const int l4 = l & 15, lh = l >> 4;
  const int bh = blockIdx.y;
  const int b = bh >> 3, h = bh & 7;
  const size_t kvbase = (size_t)b*SEQ_KV*2048 + (size_t)h*D_HEAD;

  for (int i = tid; i < 80*16; i += 256) {
    int s = i >> 4, d = (i & 15) << 3;
    half8 v = {};
    if (s < SEQ_KV) v = *(const half8*)(kv + kvbase + (size_t)s*2048 + d);
    *(half8*)(K_lds + s*136 + d) = v;
  }
  for (int i = tid; i < 96*16; i += 256) {
    int s = i >> 4, d = (i & 15) << 3;
    half8 v = {};
    if (s < SEQ_KV) v = *(const half8*)(kv + kvbase + (size_t)s*2048 + 1024 + d);
#pragma unroll
    for (int j = 0; j < 8; ++j) Vt_lds[(size_t)(d + j)*104 + s] = v[j];
  }
  {
    int rr = tid >> 2, cc = 80 + (tid & 3)*4;
    *reinterpret_cast<uint2*>(P_lds + (size_t)rr*104 + cc) = make_uint2(0u, 0u);
  }
  __syncthreads();

  const int qrow0 = blockIdx.x*64 + w*16;
  const size_t qrow = (size_t)b*SEQ_Q + qrow0 + l4;
  const size_t rowbyte = qrow*2048;
  const size_t rkey = ((size_t)((l4 >> 1) & 3)) << 4;   // (qrow>>1)&3 == (l4>>1)&3
  half8 qf[4];
#pragma unroll
  for (int kk = 0; kk < 4; ++kk) {
    size_t byte = rowbyte + (size_t)h*256 + kk*64 + lh*16;
    qf[kk] = *(const half8*)((const char*)q + (byte ^ rkey));
  }

  f32x4 sa[5] = {};
#pragma unroll
  for (int nb = 0; nb < 5; ++nb)
#pragma unroll
    for (int kk = 0; kk < 4; ++kk) {
      half8 kf = *(const half8*)(K_lds + (size_t)(nb*16 + l4)*136 + kk*32 + lh*8);
      sa[nb] = __builtin_amdgcn_mfma_f32_16x16x32_f16(qf[kk], kf, sa[nb], 0, 0, 0);
    }

  const float scale = 0.08838834764831845f;
#pragma unroll
  for (int j = 0; j < 4; ++j) {
    float pv[5];
    float mx = -1e30f;
#pragma unroll
    for (int nb = 0; nb < 5; ++nb) {
      int col = nb*16 + l4;
      float sv = (col < SEQ_KV) ? sa[nb][j]*scale : -1e30f;
      pv[nb] = sv;
      mx = fmaxf(mx, sv);
    }
    mx = fmaxf(mx, __shfl_xor(mx, 1));
    mx = fmaxf(mx, __shfl_xor(mx, 2));
    mx = fmaxf(mx, __shfl_xor(mx, 4));
    mx = fmaxf(mx, __shfl_xor(mx, 8));
    float sm = 0.f;
#pragma unroll
    for (int nb = 0; nb < 5; ++nb) { float e = __expf(pv[nb] - mx); pv[nb] = e; sm += e; }
    sm += __shfl_xor(sm, 1);
    sm += __shfl_xor(sm, 2);
    sm += __shfl_xor(sm, 4);
    sm += __shfl_xor(sm, 8);
    const float inv = 1.f / sm;
    const int prow = w*16 + lh*4 + j;
#pragma unroll
    for (int nb = 0; nb < 5; ++nb)
      P_lds[(size_t)prow*104 + nb*16 + l4] = (half_t)(pv[nb]*inv);
  }

  half8 pf[3];
#pragma unroll
  for (int kk = 0; kk < 3; ++kk)
    pf[kk] = *(const half8*)(P_lds + (size_t)(w*16 + l4)*104 + kk*32 + lh*8);
  f32x4 oa[8] = {};
#pragma unroll
  for (int nd = 0; nd < 8; ++nd)
#pragma unroll
    for (int kk = 0; kk < 3; ++kk) {
      half8 vf = *(const half8*)(Vt_lds + (size_t)(nd*16 + l4)*104 + kk*32 + lh*8);
      oa[nd] = __builtin_amdgcn_mfma_f32_16x16x32_f16(pf[kk], vf, oa[nd], 0, 0, 0);
    }
  // write O in place, swizzled
#pragma unroll
  for (int nd = 0; nd < 8; ++nd) {
#pragma unroll
    for (int j = 0; j < 4; ++j) {
      const int rl = lh*4 + j;
      const size_t row = (size_t)b*SEQ_Q + qrow0 + rl;
      size_t byte = row*2048 + (size_t)h*256 + (size_t)(nd*16 + l4)*2;
      byte ^= ((size_t)((rl >> 1) & 3)) << 4;
      *(half_t*)((char*)q + byte) = (half_t)oa[nd][j];
    }
  }
}

// ---------------- launch ----------------
extern "C" void kernel_launch(void* const* d_in, const int* in_sizes, int n_in,
                              void* d_out, int out_size, void* d_ws, size_t ws_size,
                              hipStream_t stream) {
  (void)in_sizes; (void)n_in; (void)out_size; (void)ws_size;
  const float* x  = (const float*)d_in[0];
  const float* y  = (const float*)d_in[1];
  const float* Wq = (const float*)d_in[2];
  const float* bq = (const float*)d_in[3];
  const float* Wk = (const float*)d_in[4];
  const float* bk = (const float*)d_in[5];
  const float* Wv = (const float*)d_in[6];
  const float* bv = (const float*)d_in[7];
  const float* Wo = (const float*)d_in[8];
  const float* bo = (const float*)d_in[9];

  char* ws = (char*)d_ws;
  half_t* q    = (half_t*)(ws + WS_Q);
  half_t* Wqt  = (half_t*)(ws + WS_WQT);
  half_t* Wot  = (half_t*)(ws + WS_WOT);
  half_t* Wkvt = (half_t*)(ws + WS_WKVT);
  half_t* yh   = (half_t*)(ws + WS_YH);
  half_t* kvb  = (half_t*)(ws + WS_KV);
  float*  bkv  = (float*)(ws + WS_BKV);

  dim3 tb(32, 8);
  transpose_f32f16<true ><<<dim3(32, 32), tb, 0, stream>>>(Wq, Wqt, 1024, 1024);
  transpose_f32f16<true ><<<dim3(32, 32), tb, 0, stream>>>(Wo, Wot, 1024, 1024);
  transpose_f32f16<false><<<dim3(32, 24), tb, 0, stream>>>(Wk, Wkvt, 768, 1024);
  transpose_f32f16<false><<<dim3(32, 24), tb, 0, stream>>>(Wv, Wkvt + (size_t)1024*768, 768, 1024);
  convert_pad_y<<<ROWS_KV_PAD*D_CROSS/256, 256, 0, stream>>>(y, yh);
  concat_bias<<<2*D_EMBED/256, 256, 0, stream>>>(bk, bv, bkv);

  // K/V projection: [640,768] @ [768,2048] (plain layouts)
  gemm_f16<false, false, false><<<dim3(16, 5), 256, 0, stream>>>(yh, Wkvt, bkv, kvb, ROWS_KV_PAD, 2048, 768);
  // Q projection: fp32 A fused (T14 split), dbuf prefetch, swizzles -> q (swizzled fp16)
  gemm_f16<true, false, true><<<dim3(8, 256), 256, 0, stream>>>(x, Wqt, bq, q, M_Q, 1024, 1024);
  // attention (in-place over swizzled q)
  attn_kernel<<<dim3(64, 64), 256, 0, stream>>>(q, kvb);
  // O projection: fp16 A (swizzled q), dbuf prefetch -> fp32 d_out
  gemm_f16<false, true, true><<<dim3(8, 256), 256, 0, stream>>>(q, Wot, bo, (float*)d_out, M_Q, 1024, 1024);
}